// Round 5
// baseline (3631.494 us; speedup 1.0000x reference)
//
#include <hip/hip_runtime.h>

// ---------- tiny cross-kernel state in a device global (no ws needed) ------
__device__ float g_state[512];
#define GS_FEATWN 0      // 256
#define GS_FEATBL 256    // 128
#define GS_W3D    384    // 32
#define GS_BLEND  416    // 4
#define GS_ACCS   420    // 2

// ---------- output layout (fp32 elements) ----------
#define OUT_FUSED 12582912
#define OUT_TV    13014156
#define OUT_MN    13014157
#define OUT_W3D   13014158

// ---------- fused conv1(stride1)+conv2(stride2), both relu, pad1 ----------
// grid (32,32), 256 threads; tile = 16x16 conv2 outputs (512x512 total)
// weights in original (O, I, 3, 3) layout — addresses wave-uniform.
template<int C1, int C2>
__global__ __launch_bounds__(256) void k12(
    const float* __restrict__ x,
    const float* __restrict__ w1, const float* __restrict__ b1,
    const float* __restrict__ w2, const float* __restrict__ b2,
    float* __restrict__ h2)
{
  __shared__ float xs[3][35][36];    // x halo        (15,120 B)
  __shared__ float h1s[8][33][34];   // conv1 8-oc chunk (35,904 B) -> 51 KB total
  const int tid = threadIdx.x;
  const int oy0 = blockIdx.y * 16, ox0 = blockIdx.x * 16;
  const int hy0 = 2 * oy0 - 1, hx0 = 2 * ox0 - 1;   // conv1-output region origin

  // stage x halo (region origin = hy0-1)
  for (int i = tid; i < 3675; i += 256) {
    int ic = i / 1225, rem = i - ic * 1225;
    int yy = rem / 35, xx = rem - yy * 35;
    int gy = hy0 - 1 + yy, gx = hx0 - 1 + xx;
    float v = 0.f;
    if ((unsigned)gy < 1024u && (unsigned)gx < 1024u)
      v = x[ic * 1048576 + (gy << 10) + gx];
    xs[ic][yy][xx] = v;
  }
  __syncthreads();

  float acc2[C2];
  #pragma unroll
  for (int o = 0; o < C2; o++) acc2[o] = b2[o];

  for (int ch = 0; ch < C1; ch += 8) {
    // conv1 for this 8-channel chunk over the 33x33 halo
    for (int p = tid; p < 1089; p += 256) {
      int py = p / 33, px = p - py * 33;
      int gy = hy0 + py, gx = hx0 + px;
      if ((unsigned)gy < 1024u && (unsigned)gx < 1024u) {
        float acc[8];
        #pragma unroll
        for (int o = 0; o < 8; o++) acc[o] = b1[ch + o];
        #pragma unroll
        for (int ic = 0; ic < 3; ic++)
          #pragma unroll
          for (int t = 0; t < 9; t++) {
            float v = xs[ic][py + t / 3][px + t % 3];
            #pragma unroll
            for (int o = 0; o < 8; o++)
              acc[o] = fmaf(v, w1[(ch + o) * 27 + ic * 9 + t], acc[o]);
          }
        #pragma unroll
        for (int o = 0; o < 8; o++) h1s[o][py][px] = fmaxf(acc[o], 0.f);
      } else {
        #pragma unroll
        for (int o = 0; o < 8; o++) h1s[o][py][px] = 0.f;  // conv2 zero-pad
      }
    }
    __syncthreads();

    // conv2 partial accumulate (this thread's pixel)
    {
      const int py = tid >> 4, px = tid & 15;
      #pragma unroll
      for (int ic = 0; ic < 8; ic++) {
        #pragma unroll
        for (int t = 0; t < 9; t++) {
          float v = h1s[ic][2 * py + t / 3][2 * px + t % 3];
          #pragma unroll
          for (int o = 0; o < C2; o++)
            acc2[o] = fmaf(v, w2[o * (C1 * 9) + (ch + ic) * 9 + t], acc2[o]);
        }
      }
    }
    __syncthreads();
  }

  const int py = tid >> 4, px = tid & 15;
  const int oy = oy0 + py, ox = ox0 + px;
  #pragma unroll
  for (int o = 0; o < C2; o++)
    h2[o * 262144 + (oy << 9) + ox] = fmaxf(acc2[o], 0.f);
}

// ---------- generic stride-2 conv, relu, pad1 (conv3/conv4), single batch ----
template<int CIN, int COUT>
__global__ __launch_bounds__(256) void k34(
    const float* __restrict__ in,
    const float* __restrict__ w, const float* __restrict__ bia,
    float* __restrict__ out, int HIN)
{
  const int HO = HIN >> 1;
  const int tid = threadIdx.x;
  const int py = tid >> 4, px = tid & 15;
  const int oy = blockIdx.y * 16 + py, ox = blockIdx.x * 16 + px;
  float acc[COUT];
  #pragma unroll
  for (int o = 0; o < COUT; o++) acc[o] = bia[o];
  for (int ic = 0; ic < CIN; ic++) {
    const float* p = in + ic * HIN * HIN;
    #pragma unroll
    for (int ky = 0; ky < 3; ky++) {
      int iy = 2 * oy - 1 + ky;
      #pragma unroll
      for (int kx = 0; kx < 3; kx++) {
        int ix = 2 * ox - 1 + kx;
        if ((unsigned)iy < (unsigned)HIN && (unsigned)ix < (unsigned)HIN) {
          float v = p[iy * HIN + ix];
          #pragma unroll
          for (int o = 0; o < COUT; o++)
            acc[o] = fmaf(v, w[o * (CIN * 9) + ic * 9 + ky * 3 + kx], acc[o]);
        }
      }
    }
  }
  float* ob = out + oy * HO + ox;
  #pragma unroll
  for (int o = 0; o < COUT; o++)
    ob[o * HO * HO] = fmaxf(acc[o], 0.f);
}

// ---------- global mean over 128x128 per channel (single batch) ----------
__global__ __launch_bounds__(256) void kmean(const float* __restrict__ in, int gofs) {
  const int c = blockIdx.x;
  const float* p = in + (size_t)c * 16384;
  float s = 0.f;
  for (int i = threadIdx.x; i < 16384; i += 256) s += p[i];
  __shared__ float red[256];
  red[threadIdx.x] = s; __syncthreads();
  for (int st = 128; st > 0; st >>= 1) {
    if (threadIdx.x < st) red[threadIdx.x] += red[threadIdx.x + st];
    __syncthreads();
  }
  if (threadIdx.x == 0) g_state[gofs + c] = red[0] * (1.f / 16384.f);
}

// ---------- FC head: relu(feat@fw1T+b1) @ fw2T + b2 [, sigmoid] ----------
template<int CF, int NOUT, bool SIG>
__global__ __launch_bounds__(256) void khead(
    const float* __restrict__ fw1, const float* __restrict__ fb1,
    const float* __restrict__ fw2, const float* __restrict__ fb2,
    int feato, int outo, float* out_f)
{
  __shared__ float fc1[4 * CF];
  const int tid = threadIdx.x;
  if (tid < 4 * CF) {
    int b = tid / CF, o = tid - b * CF;
    float s = fb1[o];
    for (int i = 0; i < CF; i++)
      s = fmaf(g_state[feato + b * CF + i], fw1[o * CF + i], s);
    fc1[tid] = fmaxf(s, 0.f);
  }
  __syncthreads();
  if (tid < 4 * NOUT) {
    int b = tid / NOUT, n = tid - b * NOUT;
    float s = fb2[n];
    for (int i = 0; i < CF; i++)
      s = fmaf(fc1[b * CF + i], fw2[n * CF + i], s);
    if (SIG) s = 1.f / (1.f + expf(-s));
    g_state[outo + b * NOUT + n] = s;
    if (out_f) out_f[b * NOUT + n] = s;
  }
}

// ---------- fused LUT = clip(w3d @ luts + identity, 0,1) ----------
__global__ __launch_bounds__(256) void kfuse(
    const float* __restrict__ luts, float* __restrict__ outF)
{
  if (blockIdx.x == 0 && threadIdx.x == 0) {
    g_state[GS_ACCS] = 0.f; g_state[GS_ACCS + 1] = 0.f;   // before ktv
  }
  int idx = blockIdx.x * 256 + threadIdx.x;
  if (idx >= 431244) return;
  int n = idx / 107811, m = idx - n * 107811;
  int c = m / 35937, q = m - c * 35937;
  int bq = q / 1089, r2 = q - bq * 1089;
  int gq = r2 / 33, rq = r2 - gq * 33;
  int id = (c == 0) ? rq : (c == 1) ? gq : bq;
  float s = (float)id * (1.f / 32.f);
  #pragma unroll
  for (int k = 0; k < 8; k++)
    s = fmaf(g_state[GS_W3D + n * 8 + k], luts[k * 107811 + m], s);
  s = fminf(fmaxf(s, 0.f), 1.f);
  outF[idx] = s;
}

// ---------- TV + monotonicity reductions over fused ----------
__global__ __launch_bounds__(256) void ktv(const float* __restrict__ f) {
  const int Nr = 418176;   // 4*3*33*33*32
  float tv = 0.f, mn = 0.f;
  for (int e = blockIdx.x * 256 + threadIdx.x; e < 3 * Nr; e += gridDim.x * 256) {
    int dir = e / Nr, j = e - dir * Nr;
    int i, stride; float w;
    if (dir == 0) {                        // d along r
      int r = j & 31; int t = j >> 5;
      int g = t % 33; t /= 33;
      i = t * 1089 + g * 33 + r; stride = 1;
      w = (r == 0 || r == 31) ? 2.f : 1.f;
    } else if (dir == 1) {                 // d along g
      int r = j % 33; int t = j / 33; int g = t & 31; t >>= 5;
      i = t * 1089 + g * 33 + r; stride = 33;
      w = (g == 0 || g == 31) ? 2.f : 1.f;
    } else {                               // d along b
      int r = j % 33; int t = j / 33; int g = t % 33; t /= 33;
      int bb = t & 31; t >>= 5;
      i = (t * 33 + bb) * 1089 + g * 33 + r; stride = 1089;
      w = (bb == 0 || bb == 31) ? 2.f : 1.f;
    }
    float d = f[i] - f[i + stride];
    tv = fmaf(d * d, w, tv);
    mn += fmaxf(d, 0.f);
  }
  __shared__ float r1[256], r2[256];
  r1[threadIdx.x] = tv; r2[threadIdx.x] = mn; __syncthreads();
  for (int st = 128; st > 0; st >>= 1) {
    if (threadIdx.x < st) { r1[threadIdx.x] += r1[threadIdx.x + st];
                            r2[threadIdx.x] += r2[threadIdx.x + st]; }
    __syncthreads();
  }
  if (threadIdx.x == 0) {
    atomicAdd(&g_state[GS_ACCS], r1[0]);
    atomicAdd(&g_state[GS_ACCS + 1], r2[0]);
  }
}

// ---------- trilinear apply + blend + clip; also finalize tv/mn ----------
__global__ __launch_bounds__(256) void kapply(
    const float* __restrict__ x, const float* __restrict__ F,
    float* __restrict__ out)
{
  int p = blockIdx.x * 256 + threadIdx.x;
  if (p == 0) {
    out[OUT_TV] = g_state[GS_ACCS] * (1.f / 418176.f);
    out[OUT_MN] = g_state[GS_ACCS + 1] * (1.f / 418176.f);
  }
  int b = p >> 20, yx = p & 1048575;
  size_t base = (size_t)b * 3145728u + yx;
  float xr = x[base];
  float xg = x[base + 1048576];
  float xb = x[base + 2097152];
  float a = g_state[GS_BLEND + b];
  float sr = fminf(fmaxf(xr, 0.f), 1.f) * 32.f;
  float sg = fminf(fmaxf(xg, 0.f), 1.f) * 32.f;
  float sb = fminf(fmaxf(xb, 0.f), 1.f) * 32.f;
  int ir = min((int)sr, 31), ig = min((int)sg, 31), ib = min((int)sb, 31);
  float fr = sr - ir, fg = sg - ig, fb = sb - ib;
  const float* Fb = F + (size_t)b * 107811u + ib * 1089 + ig * 33 + ir;
  #pragma unroll
  for (int c = 0; c < 3; c++) {
    const float* Fc = Fb + c * 35937;
    float v000 = Fc[0],    v001 = Fc[1];
    float v010 = Fc[33],   v011 = Fc[34];
    float v100 = Fc[1089], v101 = Fc[1090];
    float v110 = Fc[1122], v111 = Fc[1123];
    float c00 = v000 + fr * (v001 - v000);
    float c01 = v010 + fr * (v011 - v010);
    float c10 = v100 + fr * (v101 - v100);
    float c11 = v110 + fr * (v111 - v110);
    float c0 = c00 + fg * (c01 - c00);
    float c1 = c10 + fg * (c11 - c10);
    float v  = c0 + fb * (c1 - c0);
    float xv = (c == 0) ? xr : (c == 1) ? xg : xb;
    float o = fminf(fmaxf((1.f - a) * xv + a * v, 0.f), 1.f);
    out[(size_t)(b * 3 + c) * 1048576u + yx] = o;
  }
}

extern "C" void kernel_launch(void* const* d_in, const int* in_sizes, int n_in,
                              void* d_out, int out_size, void* d_ws, size_t ws_size,
                              hipStream_t stream)
{
  (void)in_sizes; (void)n_in; (void)out_size;
  const float* x    = (const float*)d_in[0];
  const float* luts = (const float*)d_in[1];
  const float* wn_w1 = (const float*)d_in[2],  *wn_b1 = (const float*)d_in[3];
  const float* wn_w2 = (const float*)d_in[4],  *wn_b2 = (const float*)d_in[5];
  const float* wn_w3 = (const float*)d_in[6],  *wn_b3 = (const float*)d_in[7];
  const float* wn_w4 = (const float*)d_in[8],  *wn_b4 = (const float*)d_in[9];
  const float* wn_fw1 = (const float*)d_in[10], *wn_fb1 = (const float*)d_in[11];
  const float* wn_fw2 = (const float*)d_in[12], *wn_fb2 = (const float*)d_in[13];
  const float* bl_w1 = (const float*)d_in[14], *bl_b1 = (const float*)d_in[15];
  const float* bl_w2 = (const float*)d_in[16], *bl_b2 = (const float*)d_in[17];
  const float* bl_w3 = (const float*)d_in[18], *bl_b3 = (const float*)d_in[19];
  const float* bl_w4 = (const float*)d_in[20], *bl_b4 = (const float*)d_in[21];
  const float* bl_fw1 = (const float*)d_in[22], *bl_fb1 = (const float*)d_in[23];
  const float* bl_fw2 = (const float*)d_in[24], *bl_fb2 = (const float*)d_in[25];
  float* out = (float*)d_out;

  // scratch: d_ws if big enough, else d_out chunk 0 (4*3*1024*1024 floats =
  // 50,331,648 B), overwritten last by kapply.
  // per-batch fp32: h2 (<=32MB) @0, h3 (<=16MB) @32MB; h4 overlays h2 region.
  float *bufA, *bufB;
  if (ws_size >= 50331648u) {
    bufA = (float*)d_ws;
    bufB = (float*)d_ws + 8388608;   // +32 MB
  } else {
    bufA = out;
    bufB = out + 8388608;
  }

  // ---- weight-net (WN), per batch ----
  for (int b = 0; b < 4; b++) {
    const float* xb = x + (size_t)b * 3u * 1048576u;
    k12<32,32><<<dim3(32,32), 256, 0, stream>>>(xb, wn_w1, wn_b1, wn_w2, wn_b2, bufA);
    k34<32,64><<<dim3(16,16), 256, 0, stream>>>(bufA, wn_w3, wn_b3, bufB, 512);
    k34<64,64><<<dim3(8,8),   256, 0, stream>>>(bufB, wn_w4, wn_b4, bufA, 256);
    kmean<<<dim3(64), 256, 0, stream>>>(bufA, GS_FEATWN + b * 64);
  }
  khead<64,8,false><<<1,256,0,stream>>>(wn_fw1, wn_fb1, wn_fw2, wn_fb2,
                                        GS_FEATWN, GS_W3D, out + OUT_W3D);

  // ---- blend-net (BL), per batch ----
  for (int b = 0; b < 4; b++) {
    const float* xb = x + (size_t)b * 3u * 1048576u;
    k12<16,16><<<dim3(32,32), 256, 0, stream>>>(xb, bl_w1, bl_b1, bl_w2, bl_b2, bufA);
    k34<16,32><<<dim3(16,16), 256, 0, stream>>>(bufA, bl_w3, bl_b3, bufB, 512);
    k34<32,32><<<dim3(8,8),   256, 0, stream>>>(bufB, bl_w4, bl_b4, bufA, 256);
    kmean<<<dim3(32), 256, 0, stream>>>(bufA, GS_FEATBL + b * 32);
  }
  khead<32,1,true ><<<1,256,0,stream>>>(bl_fw1, bl_fb1, bl_fw2, bl_fb2,
                                        GS_FEATBL, GS_BLEND, (float*)nullptr);

  // ---- LUT fuse, TV, final apply ----
  kfuse<<<1685, 256, 0, stream>>>(luts, out + OUT_FUSED);
  ktv<<<512, 256, 0, stream>>>(out + OUT_FUSED);
  kapply<<<16384, 256, 0, stream>>>(x, out + OUT_FUSED, out);
}

// Round 6
// 3299.450 us; speedup vs baseline: 1.1006x; 1.1006x over previous
//
#include <hip/hip_runtime.h>

typedef unsigned short u16;

// ---------- bf16 <-> f32 (bitwise; RNE on pack) ----------
__device__ __forceinline__ float b2f(u16 u) {
  union { unsigned int i; float f; } v; v.i = ((unsigned int)u) << 16; return v.f;
}
__device__ __forceinline__ u16 f2b(float f) {
  union { float f; unsigned int i; } v; v.f = f;
  unsigned int r = v.i + 0x7fffu + ((v.i >> 16) & 1u);
  return (u16)(r >> 16);
}

// ---------- tiny cross-kernel state in a device global ------
__device__ float g_state[512];
#define GS_FEATWN 0      // 256
#define GS_FEATBL 256    // 128
#define GS_W3D    384    // 32
#define GS_BLEND  416    // 4
#define GS_ACCS   420    // 2

// ---------- output layout (fp32 elements) ----------
#define OUT_FUSED 12582912
#define OUT_TV    13014156
#define OUT_MN    13014157
#define OUT_W3D   13014158

// ---------- fused conv1(stride1)+conv2(stride2), both relu, pad1 ----------
// grid (32,32,2) = 2 batches; 256 threads; tile = 16x16 conv2 outputs.
// x staged to LDS as bf16; conv1 chunk (8 oc) kept in LDS as bf16.
// weights fp32 from global (wave-uniform -> s_load). h2 written bf16.
template<int C1, int C2>
__global__ __launch_bounds__(256) void k12(
    const float* __restrict__ x,
    const float* __restrict__ w1, const float* __restrict__ b1,
    const float* __restrict__ w2, const float* __restrict__ b2,
    u16* __restrict__ h2)
{
  __shared__ u16 xs[3][35][36];     // 7,560 B
  __shared__ u16 h1s[8][33][34];    // 17,952 B  -> total 25.5 KB (6 blocks/CU)
  const int tid = threadIdx.x;
  const int oy0 = blockIdx.y * 16, ox0 = blockIdx.x * 16;
  const int hy0 = 2 * oy0 - 1, hx0 = 2 * ox0 - 1;
  const float* xb = x + (size_t)blockIdx.z * 3145728u;
  u16* h2b = h2 + (size_t)blockIdx.z * (size_t)C2 * 262144u;

  for (int i = tid; i < 3675; i += 256) {
    int ic = i / 1225, rem = i - ic * 1225;
    int yy = rem / 35, xx = rem - yy * 35;
    int gy = hy0 - 1 + yy, gx = hx0 - 1 + xx;
    float v = 0.f;
    if ((unsigned)gy < 1024u && (unsigned)gx < 1024u)
      v = xb[ic * 1048576 + (gy << 10) + gx];
    xs[ic][yy][xx] = f2b(v);
  }
  __syncthreads();

  float acc2[C2];
  #pragma unroll
  for (int o = 0; o < C2; o++) acc2[o] = b2[o];

  for (int ch = 0; ch < C1; ch += 8) {
    // conv1 for this 8-oc chunk over the 33x33 halo
    for (int p = tid; p < 1089; p += 256) {
      int py = p / 33, px = p - py * 33;
      int gy = hy0 + py, gx = hx0 + px;
      if ((unsigned)gy < 1024u && (unsigned)gx < 1024u) {
        float acc[8];
        #pragma unroll
        for (int o = 0; o < 8; o++) acc[o] = b1[ch + o];
        #pragma unroll
        for (int ic = 0; ic < 3; ic++)
          #pragma unroll
          for (int t = 0; t < 9; t++) {
            float v = b2f(xs[ic][py + t / 3][px + t % 3]);
            #pragma unroll
            for (int o = 0; o < 8; o++)
              acc[o] = fmaf(v, w1[(ch + o) * 27 + ic * 9 + t], acc[o]);
          }
        #pragma unroll
        for (int o = 0; o < 8; o++) h1s[o][py][px] = f2b(fmaxf(acc[o], 0.f));
      } else {
        #pragma unroll
        for (int o = 0; o < 8; o++) h1s[o][py][px] = 0;
      }
    }
    __syncthreads();

    // conv2 partial accumulate (this thread's pixel)
    {
      const int py = tid >> 4, px = tid & 15;
      #pragma unroll
      for (int ic = 0; ic < 8; ic++) {
        #pragma unroll
        for (int t = 0; t < 9; t++) {
          float v = b2f(h1s[ic][2 * py + t / 3][2 * px + t % 3]);
          #pragma unroll
          for (int o = 0; o < C2; o++)
            acc2[o] = fmaf(v, w2[o * (C1 * 9) + (ch + ic) * 9 + t], acc2[o]);
        }
      }
    }
    __syncthreads();
  }

  const int py = tid >> 4, px = tid & 15;
  const int oy = oy0 + py, ox = ox0 + px;
  #pragma unroll
  for (int o = 0; o < C2; o++)
    h2b[o * 262144 + (oy << 9) + ox] = f2b(fmaxf(acc2[o], 0.f));
}

// ---------- stride-2 conv, relu, pad1 (conv3/conv4), bf16 in/out ----------
// grid (HO/16, HO/16, 2); LDS-staged input in 8-ic chunks.
template<int CIN, int COUT>
__global__ __launch_bounds__(256) void k34(
    const u16* __restrict__ in,
    const float* __restrict__ w, const float* __restrict__ bia,
    u16* __restrict__ out, int HIN)
{
  __shared__ u16 hs[8][33][34];   // 17,952 B
  const int HO = HIN >> 1;
  const int tid = threadIdx.x;
  const int py = tid >> 4, px = tid & 15;
  const int oy0 = blockIdx.y * 16, ox0 = blockIdx.x * 16;
  const int iy0 = 2 * oy0 - 1, ix0 = 2 * ox0 - 1;
  const u16* ib = in + (size_t)blockIdx.z * (size_t)CIN * HIN * HIN;
  u16* ob = out + (size_t)blockIdx.z * (size_t)COUT * HO * HO
                + (oy0 + py) * HO + (ox0 + px);

  float acc[COUT];
  #pragma unroll
  for (int o = 0; o < COUT; o++) acc[o] = bia[o];

  for (int ch = 0; ch < CIN; ch += 8) {
    for (int i = tid; i < 8712; i += 256) {      // 8*33*33
      int ic = i / 1089, rem = i - ic * 1089;
      int yy = rem / 33, xx = rem - yy * 33;
      int gy = iy0 + yy, gx = ix0 + xx;
      u16 v = 0;
      if ((unsigned)gy < (unsigned)HIN && (unsigned)gx < (unsigned)HIN)
        v = ib[(ch + ic) * HIN * HIN + gy * HIN + gx];
      hs[ic][yy][xx] = v;
    }
    __syncthreads();

    #pragma unroll
    for (int ic = 0; ic < 8; ic++) {
      #pragma unroll
      for (int t = 0; t < 9; t++) {
        float v = b2f(hs[ic][2 * py + t / 3][2 * px + t % 3]);
        #pragma unroll
        for (int o = 0; o < COUT; o++)
          acc[o] = fmaf(v, w[o * (CIN * 9) + (ch + ic) * 9 + t], acc[o]);
      }
    }
    __syncthreads();
  }

  #pragma unroll
  for (int o = 0; o < COUT; o++)
    ob[o * HO * HO] = f2b(fmaxf(acc[o], 0.f));
}

// ---------- global mean over 128x128 per channel, 2 batches ----------
__global__ __launch_bounds__(256) void kmean(const u16* __restrict__ in,
                                             int C, int gofs) {
  const int c = blockIdx.x, z = blockIdx.y;
  const u16* p = in + ((size_t)z * C + c) * 16384;
  float s = 0.f;
  for (int i = threadIdx.x; i < 16384; i += 256) s += b2f(p[i]);
  __shared__ float red[256];
  red[threadIdx.x] = s; __syncthreads();
  for (int st = 128; st > 0; st >>= 1) {
    if (threadIdx.x < st) red[threadIdx.x] += red[threadIdx.x + st];
    __syncthreads();
  }
  if (threadIdx.x == 0) g_state[gofs + z * C + c] = red[0] * (1.f / 16384.f);
}

// ---------- FC head: relu(feat@fw1T+b1) @ fw2T + b2 [, sigmoid] ----------
template<int CF, int NOUT, bool SIG>
__global__ __launch_bounds__(256) void khead(
    const float* __restrict__ fw1, const float* __restrict__ fb1,
    const float* __restrict__ fw2, const float* __restrict__ fb2,
    int feato, int outo, float* out_f)
{
  __shared__ float fc1[4 * CF];
  const int tid = threadIdx.x;
  if (tid < 4 * CF) {
    int b = tid / CF, o = tid - b * CF;
    float s = fb1[o];
    for (int i = 0; i < CF; i++)
      s = fmaf(g_state[feato + b * CF + i], fw1[o * CF + i], s);
    fc1[tid] = fmaxf(s, 0.f);
  }
  __syncthreads();
  if (tid < 4 * NOUT) {
    int b = tid / NOUT, n = tid - b * NOUT;
    float s = fb2[n];
    for (int i = 0; i < CF; i++)
      s = fmaf(fc1[b * CF + i], fw2[n * CF + i], s);
    if (SIG) s = 1.f / (1.f + expf(-s));
    g_state[outo + b * NOUT + n] = s;
    if (out_f) out_f[b * NOUT + n] = s;
  }
}

// ---------- fused LUT = clip(w3d @ luts + identity, 0,1) ----------
__global__ __launch_bounds__(256) void kfuse(
    const float* __restrict__ luts, float* __restrict__ outF)
{
  if (blockIdx.x == 0 && threadIdx.x == 0) {
    g_state[GS_ACCS] = 0.f; g_state[GS_ACCS + 1] = 0.f;
  }
  int idx = blockIdx.x * 256 + threadIdx.x;
  if (idx >= 431244) return;
  int n = idx / 107811, m = idx - n * 107811;
  int c = m / 35937, q = m - c * 35937;
  int bq = q / 1089, r2 = q - bq * 1089;
  int gq = r2 / 33, rq = r2 - gq * 33;
  int id = (c == 0) ? rq : (c == 1) ? gq : bq;
  float s = (float)id * (1.f / 32.f);
  #pragma unroll
  for (int k = 0; k < 8; k++)
    s = fmaf(g_state[GS_W3D + n * 8 + k], luts[k * 107811 + m], s);
  s = fminf(fmaxf(s, 0.f), 1.f);
  outF[idx] = s;
}

// ---------- TV + monotonicity reductions over fused ----------
__global__ __launch_bounds__(256) void ktv(const float* __restrict__ f) {
  const int Nr = 418176;   // 4*3*33*33*32
  float tv = 0.f, mn = 0.f;
  for (int e = blockIdx.x * 256 + threadIdx.x; e < 3 * Nr; e += gridDim.x * 256) {
    int dir = e / Nr, j = e - dir * Nr;
    int i, stride; float w;
    if (dir == 0) {
      int r = j & 31; int t = j >> 5;
      int g = t % 33; t /= 33;
      i = t * 1089 + g * 33 + r; stride = 1;
      w = (r == 0 || r == 31) ? 2.f : 1.f;
    } else if (dir == 1) {
      int r = j % 33; int t = j / 33; int g = t & 31; t >>= 5;
      i = t * 1089 + g * 33 + r; stride = 33;
      w = (g == 0 || g == 31) ? 2.f : 1.f;
    } else {
      int r = j % 33; int t = j / 33; int g = t % 33; t /= 33;
      int bb = t & 31; t >>= 5;
      i = (t * 33 + bb) * 1089 + g * 33 + r; stride = 1089;
      w = (bb == 0 || bb == 31) ? 2.f : 1.f;
    }
    float d = f[i] - f[i + stride];
    tv = fmaf(d * d, w, tv);
    mn += fmaxf(d, 0.f);
  }
  __shared__ float r1[256], r2[256];
  r1[threadIdx.x] = tv; r2[threadIdx.x] = mn; __syncthreads();
  for (int st = 128; st > 0; st >>= 1) {
    if (threadIdx.x < st) { r1[threadIdx.x] += r1[threadIdx.x + st];
                            r2[threadIdx.x] += r2[threadIdx.x + st]; }
    __syncthreads();
  }
  if (threadIdx.x == 0) {
    atomicAdd(&g_state[GS_ACCS], r1[0]);
    atomicAdd(&g_state[GS_ACCS + 1], r2[0]);
  }
}

// ---------- trilinear apply + blend + clip; also finalize tv/mn ----------
__global__ __launch_bounds__(256) void kapply(
    const float* __restrict__ x, const float* __restrict__ F,
    float* __restrict__ out)
{
  int p = blockIdx.x * 256 + threadIdx.x;
  if (p == 0) {
    out[OUT_TV] = g_state[GS_ACCS] * (1.f / 418176.f);
    out[OUT_MN] = g_state[GS_ACCS + 1] * (1.f / 418176.f);
  }
  int b = p >> 20, yx = p & 1048575;
  size_t base = (size_t)b * 3145728u + yx;
  float xr = x[base];
  float xg = x[base + 1048576];
  float xb = x[base + 2097152];
  float a = g_state[GS_BLEND + b];
  float sr = fminf(fmaxf(xr, 0.f), 1.f) * 32.f;
  float sg = fminf(fmaxf(xg, 0.f), 1.f) * 32.f;
  float sb = fminf(fmaxf(xb, 0.f), 1.f) * 32.f;
  int ir = min((int)sr, 31), ig = min((int)sg, 31), ib = min((int)sb, 31);
  float fr = sr - ir, fg = sg - ig, fb = sb - ib;
  const float* Fb = F + (size_t)b * 107811u + ib * 1089 + ig * 33 + ir;
  #pragma unroll
  for (int c = 0; c < 3; c++) {
    const float* Fc = Fb + c * 35937;
    float v000 = Fc[0],    v001 = Fc[1];
    float v010 = Fc[33],   v011 = Fc[34];
    float v100 = Fc[1089], v101 = Fc[1090];
    float v110 = Fc[1122], v111 = Fc[1123];
    float c00 = v000 + fr * (v001 - v000);
    float c01 = v010 + fr * (v011 - v010);
    float c10 = v100 + fr * (v101 - v100);
    float c11 = v110 + fr * (v111 - v110);
    float c0 = c00 + fg * (c01 - c00);
    float c1 = c10 + fg * (c11 - c10);
    float v  = c0 + fb * (c1 - c0);
    float xv = (c == 0) ? xr : (c == 1) ? xg : xb;
    float o = fminf(fmaxf((1.f - a) * xv + a * v, 0.f), 1.f);
    out[(size_t)(b * 3 + c) * 1048576u + yx] = o;
  }
}

extern "C" void kernel_launch(void* const* d_in, const int* in_sizes, int n_in,
                              void* d_out, int out_size, void* d_ws, size_t ws_size,
                              hipStream_t stream)
{
  (void)in_sizes; (void)n_in; (void)out_size;
  const float* x    = (const float*)d_in[0];
  const float* luts = (const float*)d_in[1];
  const float* wn_w1 = (const float*)d_in[2],  *wn_b1 = (const float*)d_in[3];
  const float* wn_w2 = (const float*)d_in[4],  *wn_b2 = (const float*)d_in[5];
  const float* wn_w3 = (const float*)d_in[6],  *wn_b3 = (const float*)d_in[7];
  const float* wn_w4 = (const float*)d_in[8],  *wn_b4 = (const float*)d_in[9];
  const float* wn_fw1 = (const float*)d_in[10], *wn_fb1 = (const float*)d_in[11];
  const float* wn_fw2 = (const float*)d_in[12], *wn_fb2 = (const float*)d_in[13];
  const float* bl_w1 = (const float*)d_in[14], *bl_b1 = (const float*)d_in[15];
  const float* bl_w2 = (const float*)d_in[16], *bl_b2 = (const float*)d_in[17];
  const float* bl_w3 = (const float*)d_in[18], *bl_b3 = (const float*)d_in[19];
  const float* bl_w4 = (const float*)d_in[20], *bl_b4 = (const float*)d_in[21];
  const float* bl_fw1 = (const float*)d_in[22], *bl_fb1 = (const float*)d_in[23];
  const float* bl_fw2 = (const float*)d_in[24], *bl_fb2 = (const float*)d_in[25];
  float* out = (float*)d_out;

  // bf16 scratch for a 2-batch pair: h2 (<=32MB) @0, h3 (<=16MB) @32MB,
  // h4 overlays h2 region. Peak 48 MB = exactly d_out chunk 0 size.
  u16 *scrA, *scrB;
  if (ws_size >= 50331648u) {
    scrA = (u16*)d_ws;
    scrB = (u16*)d_ws + 16777216;   // +32 MB
  } else {
    scrA = (u16*)out;               // chunk 0, overwritten last by kapply
    scrB = (u16*)out + 16777216;
  }

  // ---- weight-net (WN), 2 batches per pass ----
  for (int b0 = 0; b0 < 4; b0 += 2) {
    const float* xb = x + (size_t)b0 * 3145728u;
    k12<32,32><<<dim3(32,32,2), 256, 0, stream>>>(xb, wn_w1, wn_b1, wn_w2, wn_b2, scrA);
    k34<32,64><<<dim3(16,16,2), 256, 0, stream>>>(scrA, wn_w3, wn_b3, scrB, 512);
    k34<64,64><<<dim3(8,8,2),   256, 0, stream>>>(scrB, wn_w4, wn_b4, scrA, 256);
    kmean<<<dim3(64,2), 256, 0, stream>>>(scrA, 64, GS_FEATWN + b0 * 64);
  }
  khead<64,8,false><<<1,256,0,stream>>>(wn_fw1, wn_fb1, wn_fw2, wn_fb2,
                                        GS_FEATWN, GS_W3D, out + OUT_W3D);

  // ---- blend-net (BL), 2 batches per pass ----
  for (int b0 = 0; b0 < 4; b0 += 2) {
    const float* xb = x + (size_t)b0 * 3145728u;
    k12<16,16><<<dim3(32,32,2), 256, 0, stream>>>(xb, bl_w1, bl_b1, bl_w2, bl_b2, scrA);
    k34<16,32><<<dim3(16,16,2), 256, 0, stream>>>(scrA, bl_w3, bl_b3, scrB, 512);
    k34<32,32><<<dim3(8,8,2),   256, 0, stream>>>(scrB, bl_w4, bl_b4, scrA, 256);
    kmean<<<dim3(32,2), 256, 0, stream>>>(scrA, 32, GS_FEATBL + b0 * 32);
  }
  khead<32,1,true ><<<1,256,0,stream>>>(bl_fw1, bl_fb1, bl_fw2, bl_fb2,
                                        GS_FEATBL, GS_BLEND, (float*)nullptr);

  // ---- LUT fuse, TV, final apply ----
  kfuse<<<1685, 256, 0, stream>>>(luts, out + OUT_FUSED);
  ktv<<<512, 256, 0, stream>>>(out + OUT_FUSED);
  kapply<<<16384, 256, 0, stream>>>(x, out + OUT_FUSED, out);
}

// Round 7
// 2606.123 us; speedup vs baseline: 1.3934x; 1.2660x over previous
//
#include <hip/hip_runtime.h>

typedef unsigned short u16;

// ---------- bf16 <-> f32 (bitwise; RNE on pack) ----------
__device__ __forceinline__ float b2f(u16 u) {
  union { unsigned int i; float f; } v; v.i = ((unsigned int)u) << 16; return v.f;
}
__device__ __forceinline__ u16 f2b(float f) {
  union { float f; unsigned int i; } v; v.f = f;
  unsigned int r = v.i + 0x7fffu + ((v.i >> 16) & 1u);
  return (u16)(r >> 16);
}

// ---------- tiny cross-kernel state ------
__device__ float g_state[512];
#define GS_FEATWN 0      // 256
#define GS_FEATBL 256    // 128
#define GS_W3D    384    // 32
#define GS_BLEND  416    // 4
#define GS_ACCS   420    // 2

// ---------- transposed conv weight tables: (ic*9+t, oc), fp32 ----------
__device__ float g_wt[81936];
#define WT_WN1 0       // 27 x 32
#define WT_WN2 864     // 288 x 32
#define WT_WN3 10080   // 288 x 64
#define WT_WN4 28512   // 576 x 64
#define WT_BL1 65376   // 27 x 16
#define WT_BL2 65808   // 144 x 16
#define WT_BL3 68112   // 144 x 32
#define WT_BL4 72720   // 288 x 32

// ---------- output layout (fp32 elements) ----------
#define OUT_FUSED 12582912
#define OUT_TV    13014156
#define OUT_MN    13014157
#define OUT_W3D   13014158

// ---------- prep: transpose conv weights (O,I,3,3) -> (I*9, O) ----------
struct PrepDesc { const float* src; int O; int IKK; int dst; };
struct PrepArgs { PrepDesc d[8]; };

__global__ __launch_bounds__(256) void kprep(PrepArgs a) {
  PrepDesc t = a.d[blockIdx.x];
  int n = t.O * t.IKK;
  for (int e = threadIdx.x; e < n; e += 256) {
    int o = e / t.IKK, r = e - o * t.IKK;
    g_wt[t.dst + r * t.O + o] = t.src[e];
  }
}

// ---------- fused conv1(stride1)+conv2(stride2), both relu, pad1 ----------
// grid (32,32,2); 256 threads; tile = 16x16 conv2 outputs.
// Weights for each 8-ic chunk staged into LDS (fp32, transposed layout).
template<int C1, int C2>
__global__ __launch_bounds__(256) void k12(
    const float* __restrict__ x, int w1o, const float* __restrict__ b1,
    int w2o, const float* __restrict__ b2, u16* __restrict__ h2)
{
  __shared__ u16 xs[3][35][36];      // 7,560 B
  __shared__ u16 h1s[8][33][34];     // 17,952 B
  __shared__ float w1s[27 * 8];      // 864 B
  __shared__ float w2s[72 * C2];     // C2=32: 9,216 B -> total ~35.6 KB
  const int tid = threadIdx.x;
  const int oy0 = blockIdx.y * 16, ox0 = blockIdx.x * 16;
  const int hy0 = 2 * oy0 - 1, hx0 = 2 * ox0 - 1;
  const float* xb = x + (size_t)blockIdx.z * 3145728u;
  u16* h2b = h2 + (size_t)blockIdx.z * (size_t)C2 * 262144u;

  for (int i = tid; i < 3675; i += 256) {
    int ic = i / 1225, rem = i - ic * 1225;
    int yy = rem / 35, xx = rem - yy * 35;
    int gy = hy0 - 1 + yy, gx = hx0 - 1 + xx;
    float v = 0.f;
    if ((unsigned)gy < 1024u && (unsigned)gx < 1024u)
      v = xb[ic * 1048576 + (gy << 10) + gx];
    xs[ic][yy][xx] = f2b(v);
  }

  float acc2[C2];
  #pragma unroll
  for (int o = 0; o < C2; o++) acc2[o] = b2[o];

  for (int ch = 0; ch < C1; ch += 8) {
    // stage this chunk's weights (contiguous / coalesced from g_wt)
    if (tid < 216) {                     // 27 rows x 8 oc
      int r = tid >> 3, o = tid & 7;
      w1s[tid] = g_wt[w1o + r * C1 + ch + o];
    }
    for (int i = tid; i < 72 * C2; i += 256)
      w2s[i] = g_wt[w2o + ch * 9 * C2 + i];
    __syncthreads();                     // weights ready; prev-chunk reads done

    // conv1 for this 8-oc chunk over the 33x33 halo
    for (int p = tid; p < 1089; p += 256) {
      int py = p / 33, px = p - py * 33;
      int gy = hy0 + py, gx = hx0 + px;
      if ((unsigned)gy < 1024u && (unsigned)gx < 1024u) {
        float acc[8];
        #pragma unroll
        for (int o = 0; o < 8; o++) acc[o] = b1[ch + o];
        #pragma unroll
        for (int ic = 0; ic < 3; ic++)
          #pragma unroll
          for (int t = 0; t < 9; t++) {
            float v = b2f(xs[ic][py + t / 3][px + t % 3]);
            const float* wr = &w1s[(ic * 9 + t) * 8];
            #pragma unroll
            for (int o = 0; o < 8; o++)
              acc[o] = fmaf(v, wr[o], acc[o]);
          }
        #pragma unroll
        for (int o = 0; o < 8; o++) h1s[o][py][px] = f2b(fmaxf(acc[o], 0.f));
      } else {
        #pragma unroll
        for (int o = 0; o < 8; o++) h1s[o][py][px] = 0;
      }
    }
    __syncthreads();

    // conv2 partial accumulate (this thread's pixel)
    {
      const int py = tid >> 4, px = tid & 15;
      #pragma unroll
      for (int ic = 0; ic < 8; ic++) {
        #pragma unroll
        for (int t = 0; t < 9; t++) {
          float v = b2f(h1s[ic][2 * py + t / 3][2 * px + t % 3]);
          const float* wr = &w2s[(ic * 9 + t) * C2];
          #pragma unroll
          for (int o = 0; o < C2; o++)
            acc2[o] = fmaf(v, wr[o], acc2[o]);
        }
      }
    }
    __syncthreads();
  }

  const int py = tid >> 4, px = tid & 15;
  const int oy = oy0 + py, ox = ox0 + px;
  #pragma unroll
  for (int o = 0; o < C2; o++)
    h2b[o * 262144 + (oy << 9) + ox] = f2b(fmaxf(acc2[o], 0.f));
}

// ---------- stride-2 conv, relu, pad1 (conv3/conv4), bf16 in/out ----------
// grid (HO/16, HO/16, 2*OCG); each block computes OCB output channels.
// Input chunk + chunk weights staged in LDS.
template<int CIN, int COUT, int OCB>
__global__ __launch_bounds__(256) void k34(
    const u16* __restrict__ in, int wo, const float* __restrict__ bia,
    u16* __restrict__ out, int HIN)
{
  constexpr int OCG = COUT / OCB;
  __shared__ u16 hs[8][33][34];        // 17,952 B
  __shared__ float wchunk[72 * OCB];   // OCB=32: 9,216 B ; OCB=16: 4,608 B
  const int HO = HIN >> 1;
  const int tid = threadIdx.x;
  const int py = tid >> 4, px = tid & 15;
  const int zb = blockIdx.z / OCG;           // batch
  const int og = blockIdx.z - zb * OCG;      // oc-group
  const int oc0 = og * OCB;
  const int oy0 = blockIdx.y * 16, ox0 = blockIdx.x * 16;
  const int iy0 = 2 * oy0 - 1, ix0 = 2 * ox0 - 1;
  const u16* ib = in + (size_t)zb * (size_t)CIN * HIN * HIN;
  u16* ob = out + (size_t)zb * (size_t)COUT * HO * HO
                + (size_t)oc0 * HO * HO + (oy0 + py) * HO + (ox0 + px);

  float acc[OCB];
  #pragma unroll
  for (int o = 0; o < OCB; o++) acc[o] = bia[oc0 + o];

  for (int ch = 0; ch < CIN; ch += 8) {
    for (int i = tid; i < 8712; i += 256) {      // 8*33*33 input chunk
      int ic = i / 1089, rem = i - ic * 1089;
      int yy = rem / 33, xx = rem - yy * 33;
      int gy = iy0 + yy, gx = ix0 + xx;
      u16 v = 0;
      if ((unsigned)gy < (unsigned)HIN && (unsigned)gx < (unsigned)HIN)
        v = ib[(ch + ic) * HIN * HIN + gy * HIN + gx];
      hs[ic][yy][xx] = v;
    }
    for (int i = tid; i < 72 * OCB; i += 256) {  // chunk weights
      int r = i / OCB, o = i & (OCB - 1);
      wchunk[i] = g_wt[wo + (ch * 9 + r) * COUT + oc0 + o];
    }
    __syncthreads();

    #pragma unroll
    for (int ic = 0; ic < 8; ic++) {
      #pragma unroll
      for (int t = 0; t < 9; t++) {
        float v = b2f(hs[ic][2 * py + t / 3][2 * px + t % 3]);
        const float* wr = &wchunk[(ic * 9 + t) * OCB];
        #pragma unroll
        for (int o = 0; o < OCB; o++)
          acc[o] = fmaf(v, wr[o], acc[o]);
      }
    }
    __syncthreads();
  }

  #pragma unroll
  for (int o = 0; o < OCB; o++)
    ob[o * HO * HO] = f2b(fmaxf(acc[o], 0.f));
}

// ---------- global mean over 128x128 per channel, 2 batches ----------
__global__ __launch_bounds__(256) void kmean(const u16* __restrict__ in,
                                             int C, int gofs) {
  const int c = blockIdx.x, z = blockIdx.y;
  const u16* p = in + ((size_t)z * C + c) * 16384;
  float s = 0.f;
  for (int i = threadIdx.x; i < 16384; i += 256) s += b2f(p[i]);
  __shared__ float red[256];
  red[threadIdx.x] = s; __syncthreads();
  for (int st = 128; st > 0; st >>= 1) {
    if (threadIdx.x < st) red[threadIdx.x] += red[threadIdx.x + st];
    __syncthreads();
  }
  if (threadIdx.x == 0) g_state[gofs + z * C + c] = red[0] * (1.f / 16384.f);
}

// ---------- FC head ----------
template<int CF, int NOUT, bool SIG>
__global__ __launch_bounds__(256) void khead(
    const float* __restrict__ fw1, const float* __restrict__ fb1,
    const float* __restrict__ fw2, const float* __restrict__ fb2,
    int feato, int outo, float* out_f)
{
  __shared__ float fc1[4 * CF];
  const int tid = threadIdx.x;
  if (tid < 4 * CF) {
    int b = tid / CF, o = tid - b * CF;
    float s = fb1[o];
    for (int i = 0; i < CF; i++)
      s = fmaf(g_state[feato + b * CF + i], fw1[o * CF + i], s);
    fc1[tid] = fmaxf(s, 0.f);
  }
  __syncthreads();
  if (tid < 4 * NOUT) {
    int b = tid / NOUT, n = tid - b * NOUT;
    float s = fb2[n];
    for (int i = 0; i < CF; i++)
      s = fmaf(fc1[b * CF + i], fw2[n * CF + i], s);
    if (SIG) s = 1.f / (1.f + expf(-s));
    g_state[outo + b * NOUT + n] = s;
    if (out_f) out_f[b * NOUT + n] = s;
  }
}

// ---------- fused LUT = clip(w3d @ luts + identity, 0,1) ----------
__global__ __launch_bounds__(256) void kfuse(
    const float* __restrict__ luts, float* __restrict__ outF)
{
  if (blockIdx.x == 0 && threadIdx.x == 0) {
    g_state[GS_ACCS] = 0.f; g_state[GS_ACCS + 1] = 0.f;
  }
  int idx = blockIdx.x * 256 + threadIdx.x;
  if (idx >= 431244) return;
  int n = idx / 107811, m = idx - n * 107811;
  int c = m / 35937, q = m - c * 35937;
  int bq = q / 1089, r2 = q - bq * 1089;
  int gq = r2 / 33, rq = r2 - gq * 33;
  int id = (c == 0) ? rq : (c == 1) ? gq : bq;
  float s = (float)id * (1.f / 32.f);
  #pragma unroll
  for (int k = 0; k < 8; k++)
    s = fmaf(g_state[GS_W3D + n * 8 + k], luts[k * 107811 + m], s);
  s = fminf(fmaxf(s, 0.f), 1.f);
  outF[idx] = s;
}

// ---------- TV + monotonicity reductions over fused ----------
__global__ __launch_bounds__(256) void ktv(const float* __restrict__ f) {
  const int Nr = 418176;   // 4*3*33*33*32
  float tv = 0.f, mn = 0.f;
  for (int e = blockIdx.x * 256 + threadIdx.x; e < 3 * Nr; e += gridDim.x * 256) {
    int dir = e / Nr, j = e - dir * Nr;
    int i, stride; float w;
    if (dir == 0) {
      int r = j & 31; int t = j >> 5;
      int g = t % 33; t /= 33;
      i = t * 1089 + g * 33 + r; stride = 1;
      w = (r == 0 || r == 31) ? 2.f : 1.f;
    } else if (dir == 1) {
      int r = j % 33; int t = j / 33; int g = t & 31; t >>= 5;
      i = t * 1089 + g * 33 + r; stride = 33;
      w = (g == 0 || g == 31) ? 2.f : 1.f;
    } else {
      int r = j % 33; int t = j / 33; int g = t % 33; t /= 33;
      int bb = t & 31; t >>= 5;
      i = (t * 33 + bb) * 1089 + g * 33 + r; stride = 1089;
      w = (bb == 0 || bb == 31) ? 2.f : 1.f;
    }
    float d = f[i] - f[i + stride];
    tv = fmaf(d * d, w, tv);
    mn += fmaxf(d, 0.f);
  }
  __shared__ float r1[256], r2[256];
  r1[threadIdx.x] = tv; r2[threadIdx.x] = mn; __syncthreads();
  for (int st = 128; st > 0; st >>= 1) {
    if (threadIdx.x < st) { r1[threadIdx.x] += r1[threadIdx.x + st];
                            r2[threadIdx.x] += r2[threadIdx.x + st]; }
    __syncthreads();
  }
  if (threadIdx.x == 0) {
    atomicAdd(&g_state[GS_ACCS], r1[0]);
    atomicAdd(&g_state[GS_ACCS + 1], r2[0]);
  }
}

// ---------- trilinear apply + blend + clip; finalize tv/mn ----------
__global__ __launch_bounds__(256) void kapply(
    const float* __restrict__ x, const float* __restrict__ F,
    float* __restrict__ out)
{
  int p = blockIdx.x * 256 + threadIdx.x;
  if (p == 0) {
    out[OUT_TV] = g_state[GS_ACCS] * (1.f / 418176.f);
    out[OUT_MN] = g_state[GS_ACCS + 1] * (1.f / 418176.f);
  }
  int b = p >> 20, yx = p & 1048575;
  size_t base = (size_t)b * 3145728u + yx;
  float xr = x[base];
  float xg = x[base + 1048576];
  float xb = x[base + 2097152];
  float a = g_state[GS_BLEND + b];
  float sr = fminf(fmaxf(xr, 0.f), 1.f) * 32.f;
  float sg = fminf(fmaxf(xg, 0.f), 1.f) * 32.f;
  float sb = fminf(fmaxf(xb, 0.f), 1.f) * 32.f;
  int ir = min((int)sr, 31), ig = min((int)sg, 31), ib = min((int)sb, 31);
  float fr = sr - ir, fg = sg - ig, fb = sb - ib;
  const float* Fb = F + (size_t)b * 107811u + ib * 1089 + ig * 33 + ir;
  #pragma unroll
  for (int c = 0; c < 3; c++) {
    const float* Fc = Fb + c * 35937;
    float v000 = Fc[0],    v001 = Fc[1];
    float v010 = Fc[33],   v011 = Fc[34];
    float v100 = Fc[1089], v101 = Fc[1090];
    float v110 = Fc[1122], v111 = Fc[1123];
    float c00 = v000 + fr * (v001 - v000);
    float c01 = v010 + fr * (v011 - v010);
    float c10 = v100 + fr * (v101 - v100);
    float c11 = v110 + fr * (v111 - v110);
    float c0 = c00 + fg * (c01 - c00);
    float c1 = c10 + fg * (c11 - c10);
    float v  = c0 + fb * (c1 - c0);
    float xv = (c == 0) ? xr : (c == 1) ? xg : xb;
    float o = fminf(fmaxf((1.f - a) * xv + a * v, 0.f), 1.f);
    out[(size_t)(b * 3 + c) * 1048576u + yx] = o;
  }
}

extern "C" void kernel_launch(void* const* d_in, const int* in_sizes, int n_in,
                              void* d_out, int out_size, void* d_ws, size_t ws_size,
                              hipStream_t stream)
{
  (void)in_sizes; (void)n_in; (void)out_size;
  const float* x    = (const float*)d_in[0];
  const float* luts = (const float*)d_in[1];
  const float* wn_b1 = (const float*)d_in[3];
  const float* wn_b2 = (const float*)d_in[5];
  const float* wn_b3 = (const float*)d_in[7];
  const float* wn_b4 = (const float*)d_in[9];
  const float* wn_fw1 = (const float*)d_in[10], *wn_fb1 = (const float*)d_in[11];
  const float* wn_fw2 = (const float*)d_in[12], *wn_fb2 = (const float*)d_in[13];
  const float* bl_b1 = (const float*)d_in[15];
  const float* bl_b2 = (const float*)d_in[17];
  const float* bl_b3 = (const float*)d_in[19];
  const float* bl_b4 = (const float*)d_in[21];
  const float* bl_fw1 = (const float*)d_in[22], *bl_fb1 = (const float*)d_in[23];
  const float* bl_fw2 = (const float*)d_in[24], *bl_fb2 = (const float*)d_in[25];
  float* out = (float*)d_out;

  // bf16 scratch for a 2-batch pair: h2 @0 (<=32MB), h3 @32MB (<=16MB);
  // h4 overlays h2 region. Peak 48 MB = d_out chunk 0 (overwritten last).
  u16 *scrA, *scrB;
  if (ws_size >= 50331648u) {
    scrA = (u16*)d_ws;
    scrB = (u16*)d_ws + 16777216;
  } else {
    scrA = (u16*)out;
    scrB = (u16*)out + 16777216;
  }

  PrepArgs pa;
  const float* src[8] = {(const float*)d_in[2], (const float*)d_in[4],
                         (const float*)d_in[6], (const float*)d_in[8],
                         (const float*)d_in[14], (const float*)d_in[16],
                         (const float*)d_in[18], (const float*)d_in[20]};
  const int O[8]   = {32, 32, 64, 64, 16, 16, 32, 32};
  const int IKK[8] = {27, 288, 288, 576, 27, 144, 144, 288};
  const int DST[8] = {WT_WN1, WT_WN2, WT_WN3, WT_WN4,
                      WT_BL1, WT_BL2, WT_BL3, WT_BL4};
  for (int t = 0; t < 8; t++) {
    pa.d[t].src = src[t]; pa.d[t].O = O[t];
    pa.d[t].IKK = IKK[t]; pa.d[t].dst = DST[t];
  }
  kprep<<<dim3(8), 256, 0, stream>>>(pa);

  // ---- weight-net (WN), 2 batches per pass ----
  for (int b0 = 0; b0 < 4; b0 += 2) {
    const float* xb = x + (size_t)b0 * 3145728u;
    k12<32,32><<<dim3(32,32,2), 256, 0, stream>>>(xb, WT_WN1, wn_b1, WT_WN2, wn_b2, scrA);
    k34<32,64,32><<<dim3(16,16,4), 256, 0, stream>>>(scrA, WT_WN3, wn_b3, scrB, 512);
    k34<64,64,16><<<dim3(8,8,8),   256, 0, stream>>>(scrB, WT_WN4, wn_b4, scrA, 256);
    kmean<<<dim3(64,2), 256, 0, stream>>>(scrA, 64, GS_FEATWN + b0 * 64);
  }
  khead<64,8,false><<<1,256,0,stream>>>(wn_fw1, wn_fb1, wn_fw2, wn_fb2,
                                        GS_FEATWN, GS_W3D, out + OUT_W3D);

  // ---- blend-net (BL), 2 batches per pass ----
  for (int b0 = 0; b0 < 4; b0 += 2) {
    const float* xb = x + (size_t)b0 * 3145728u;
    k12<16,16><<<dim3(32,32,2), 256, 0, stream>>>(xb, WT_BL1, bl_b1, WT_BL2, bl_b2, scrA);
    k34<16,32,32><<<dim3(16,16,2), 256, 0, stream>>>(scrA, WT_BL3, bl_b3, scrB, 512);
    k34<32,32,16><<<dim3(8,8,4),   256, 0, stream>>>(scrB, WT_BL4, bl_b4, scrA, 256);
    kmean<<<dim3(32,2), 256, 0, stream>>>(scrA, 32, GS_FEATBL + b0 * 32);
  }
  khead<32,1,true ><<<1,256,0,stream>>>(bl_fw1, bl_fb1, bl_fw2, bl_fb2,
                                        GS_FEATBL, GS_BLEND, (float*)nullptr);

  // ---- LUT fuse, TV, final apply ----
  kfuse<<<1685, 256, 0, stream>>>(luts, out + OUT_FUSED);
  ktv<<<512, 256, 0, stream>>>(out + OUT_FUSED);
  kapply<<<16384, 256, 0, stream>>>(x, out + OUT_FUSED, out);
}

// Round 8
// 1760.336 us; speedup vs baseline: 2.0630x; 1.4805x over previous
//
#include <hip/hip_runtime.h>

typedef unsigned short u16;

// ---------- bf16 <-> f32 (bitwise; RNE on pack) ----------
__device__ __forceinline__ float b2f(u16 u) {
  union { unsigned int i; float f; } v; v.i = ((unsigned int)u) << 16; return v.f;
}
__device__ __forceinline__ u16 f2b(float f) {
  union { float f; unsigned int i; } v; v.f = f;
  unsigned int r = v.i + 0x7fffu + ((v.i >> 16) & 1u);
  return (u16)(r >> 16);
}

// ---------- tiny cross-kernel state ------
__device__ float g_state[512];
#define GS_FEATWN 0      // 256
#define GS_FEATBL 256    // 128
#define GS_W3D    384    // 32
#define GS_BLEND  416    // 4
#define GS_ACCS   420    // 2

// ---------- transposed conv weight tables: (ic*9+t, oc), fp32 ----------
__device__ float g_wt[81936];
#define WT_WN1 0       // 27 x 32
#define WT_WN2 864     // 288 x 32
#define WT_WN3 10080   // 288 x 64
#define WT_WN4 28512   // 576 x 64
#define WT_BL1 65376   // 27 x 16
#define WT_BL2 65808   // 144 x 16
#define WT_BL3 68112   // 144 x 32
#define WT_BL4 72720   // 288 x 32

// ---------- output layout (fp32 elements) ----------
#define OUT_FUSED 12582912
#define OUT_TV    13014156
#define OUT_MN    13014157
#define OUT_W3D   13014158

// ---------- prep: transpose conv weights (O,I,3,3) -> (I*9, O) ----------
struct PrepDesc { const float* src; int O; int IKK; int dst; };
struct PrepArgs { PrepDesc d[8]; };

__global__ __launch_bounds__(256) void kprep(PrepArgs a) {
  PrepDesc t = a.d[blockIdx.x];
  int n = t.O * t.IKK;
  for (int e = threadIdx.x; e < n; e += 256) {
    int o = e / t.IKK, r = e - o * t.IKK;
    g_wt[t.dst + r * t.O + o] = t.src[e];
  }
}

// ---------- fused conv1(stride1)+conv2(stride2), both relu, pad1 ----------
// grid (32,32,2); 256 threads; tile = 16x16 conv2 outputs.
// Weights: wave-uniform fp32 reads from g_wt -> s_load broadcasts (no VGPR /
// LDS cost). Activations staged in LDS as bf16 (25.5 KB -> 6 blocks/CU).
template<int C1, int C2>
__global__ __launch_bounds__(256) void k12(
    const float* __restrict__ x, int w1o, const float* __restrict__ b1,
    int w2o, const float* __restrict__ b2, u16* __restrict__ h2)
{
  __shared__ u16 xs[3][35][36];      // 7,560 B
  __shared__ u16 h1s[8][33][34];     // 17,952 B -> 25.5 KB total
  const int tid = threadIdx.x;
  const int oy0 = blockIdx.y * 16, ox0 = blockIdx.x * 16;
  const int hy0 = 2 * oy0 - 1, hx0 = 2 * ox0 - 1;
  const float* xb = x + (size_t)blockIdx.z * 3145728u;
  u16* h2b = h2 + (size_t)blockIdx.z * (size_t)C2 * 262144u;

  for (int i = tid; i < 3675; i += 256) {
    int ic = i / 1225, rem = i - ic * 1225;
    int yy = rem / 35, xx = rem - yy * 35;
    int gy = hy0 - 1 + yy, gx = hx0 - 1 + xx;
    float v = 0.f;
    if ((unsigned)gy < 1024u && (unsigned)gx < 1024u)
      v = xb[ic * 1048576 + (gy << 10) + gx];
    xs[ic][yy][xx] = f2b(v);
  }
  __syncthreads();

  float acc2[C2];
  #pragma unroll
  for (int o = 0; o < C2; o++) acc2[o] = b2[o];

  for (int ch = 0; ch < C1; ch += 8) {
    // conv1 for this 8-oc chunk over the 33x33 halo
    for (int p = tid; p < 1089; p += 256) {
      int py = p / 33, px = p - py * 33;
      int gy = hy0 + py, gx = hx0 + px;
      if ((unsigned)gy < 1024u && (unsigned)gx < 1024u) {
        float acc[8];
        #pragma unroll
        for (int o = 0; o < 8; o++) acc[o] = b1[ch + o];
        #pragma unroll
        for (int ic = 0; ic < 3; ic++)
          #pragma unroll
          for (int t = 0; t < 9; t++) {
            float v = b2f(xs[ic][py + t / 3][px + t % 3]);
            const float* wr = &g_wt[w1o + (ic * 9 + t) * C1 + ch];
            #pragma unroll
            for (int o = 0; o < 8; o++)
              acc[o] = fmaf(v, wr[o], acc[o]);
          }
        #pragma unroll
        for (int o = 0; o < 8; o++) h1s[o][py][px] = f2b(fmaxf(acc[o], 0.f));
      } else {
        #pragma unroll
        for (int o = 0; o < 8; o++) h1s[o][py][px] = 0;
      }
    }
    __syncthreads();

    // conv2 partial accumulate (this thread's pixel)
    {
      const int py = tid >> 4, px = tid & 15;
      #pragma unroll
      for (int ic = 0; ic < 8; ic++) {
        #pragma unroll
        for (int t = 0; t < 9; t++) {
          float v = b2f(h1s[ic][2 * py + t / 3][2 * px + t % 3]);
          const float* wr = &g_wt[w2o + ((ch + ic) * 9 + t) * C2];
          #pragma unroll
          for (int o = 0; o < C2; o++)
            acc2[o] = fmaf(v, wr[o], acc2[o]);
        }
      }
    }
    __syncthreads();
  }

  const int py = tid >> 4, px = tid & 15;
  const int oy = oy0 + py, ox = ox0 + px;
  #pragma unroll
  for (int o = 0; o < C2; o++)
    h2b[o * 262144 + (oy << 9) + ox] = f2b(fmaxf(acc2[o], 0.f));
}

// ---------- stride-2 conv, relu, pad1 (conv3/conv4), bf16 in/out ----------
// grid (HO/16, HO/16, 2*OCG); each block computes OCB output channels.
// Input chunk + chunk weights staged in LDS.
template<int CIN, int COUT, int OCB>
__global__ __launch_bounds__(256) void k34(
    const u16* __restrict__ in, int wo, const float* __restrict__ bia,
    u16* __restrict__ out, int HIN)
{
  constexpr int OCG = COUT / OCB;
  __shared__ u16 hs[8][33][34];        // 17,952 B
  __shared__ float wchunk[72 * OCB];   // OCB=32: 9,216 B ; OCB=16: 4,608 B
  const int HO = HIN >> 1;
  const int tid = threadIdx.x;
  const int py = tid >> 4, px = tid & 15;
  const int zb = blockIdx.z / OCG;           // batch
  const int og = blockIdx.z - zb * OCG;      // oc-group
  const int oc0 = og * OCB;
  const int oy0 = blockIdx.y * 16, ox0 = blockIdx.x * 16;
  const int iy0 = 2 * oy0 - 1, ix0 = 2 * ox0 - 1;
  const u16* ib = in + (size_t)zb * (size_t)CIN * HIN * HIN;
  u16* ob = out + (size_t)zb * (size_t)COUT * HO * HO
                + (size_t)oc0 * HO * HO + (oy0 + py) * HO + (ox0 + px);

  float acc[OCB];
  #pragma unroll
  for (int o = 0; o < OCB; o++) acc[o] = bia[oc0 + o];

  for (int ch = 0; ch < CIN; ch += 8) {
    for (int i = tid; i < 8712; i += 256) {      // 8*33*33 input chunk
      int ic = i / 1089, rem = i - ic * 1089;
      int yy = rem / 33, xx = rem - yy * 33;
      int gy = iy0 + yy, gx = ix0 + xx;
      u16 v = 0;
      if ((unsigned)gy < (unsigned)HIN && (unsigned)gx < (unsigned)HIN)
        v = ib[(ch + ic) * HIN * HIN + gy * HIN + gx];
      hs[ic][yy][xx] = v;
    }
    for (int i = tid; i < 72 * OCB; i += 256) {  // chunk weights
      int r = i / OCB, o = i & (OCB - 1);
      wchunk[i] = g_wt[wo + (ch * 9 + r) * COUT + oc0 + o];
    }
    __syncthreads();

    #pragma unroll
    for (int ic = 0; ic < 8; ic++) {
      #pragma unroll
      for (int t = 0; t < 9; t++) {
        float v = b2f(hs[ic][2 * py + t / 3][2 * px + t % 3]);
        const float* wr = &wchunk[(ic * 9 + t) * OCB];
        #pragma unroll
        for (int o = 0; o < OCB; o++)
          acc[o] = fmaf(v, wr[o], acc[o]);
      }
    }
    __syncthreads();
  }

  #pragma unroll
  for (int o = 0; o < OCB; o++)
    ob[o * HO * HO] = f2b(fmaxf(acc[o], 0.f));
}

// ---------- global mean over 128x128 per channel, 2 batches ----------
__global__ __launch_bounds__(256) void kmean(const u16* __restrict__ in,
                                             int C, int gofs) {
  const int c = blockIdx.x, z = blockIdx.y;
  const u16* p = in + ((size_t)z * C + c) * 16384;
  float s = 0.f;
  for (int i = threadIdx.x; i < 16384; i += 256) s += b2f(p[i]);
  __shared__ float red[256];
  red[threadIdx.x] = s; __syncthreads();
  for (int st = 128; st > 0; st >>= 1) {
    if (threadIdx.x < st) red[threadIdx.x] += red[threadIdx.x + st];
    __syncthreads();
  }
  if (threadIdx.x == 0) g_state[gofs + z * C + c] = red[0] * (1.f / 16384.f);
}

// ---------- FC head ----------
template<int CF, int NOUT, bool SIG>
__global__ __launch_bounds__(256) void khead(
    const float* __restrict__ fw1, const float* __restrict__ fb1,
    const float* __restrict__ fw2, const float* __restrict__ fb2,
    int feato, int outo, float* out_f)
{
  __shared__ float fc1[4 * CF];
  const int tid = threadIdx.x;
  if (tid < 4 * CF) {
    int b = tid / CF, o = tid - b * CF;
    float s = fb1[o];
    for (int i = 0; i < CF; i++)
      s = fmaf(g_state[feato + b * CF + i], fw1[o * CF + i], s);
    fc1[tid] = fmaxf(s, 0.f);
  }
  __syncthreads();
  if (tid < 4 * NOUT) {
    int b = tid / NOUT, n = tid - b * NOUT;
    float s = fb2[n];
    for (int i = 0; i < CF; i++)
      s = fmaf(fc1[b * CF + i], fw2[n * CF + i], s);
    if (SIG) s = 1.f / (1.f + expf(-s));
    g_state[outo + b * NOUT + n] = s;
    if (out_f) out_f[b * NOUT + n] = s;
  }
}

// ---------- fused LUT = clip(w3d @ luts + identity, 0,1) ----------
__global__ __launch_bounds__(256) void kfuse(
    const float* __restrict__ luts, float* __restrict__ outF)
{
  if (blockIdx.x == 0 && threadIdx.x == 0) {
    g_state[GS_ACCS] = 0.f; g_state[GS_ACCS + 1] = 0.f;
  }
  int idx = blockIdx.x * 256 + threadIdx.x;
  if (idx >= 431244) return;
  int n = idx / 107811, m = idx - n * 107811;
  int c = m / 35937, q = m - c * 35937;
  int bq = q / 1089, r2 = q - bq * 1089;
  int gq = r2 / 33, rq = r2 - gq * 33;
  int id = (c == 0) ? rq : (c == 1) ? gq : bq;
  float s = (float)id * (1.f / 32.f);
  #pragma unroll
  for (int k = 0; k < 8; k++)
    s = fmaf(g_state[GS_W3D + n * 8 + k], luts[k * 107811 + m], s);
  s = fminf(fmaxf(s, 0.f), 1.f);
  outF[idx] = s;
}

// ---------- TV + monotonicity reductions over fused ----------
__global__ __launch_bounds__(256) void ktv(const float* __restrict__ f) {
  const int Nr = 418176;   // 4*3*33*33*32
  float tv = 0.f, mn = 0.f;
  for (int e = blockIdx.x * 256 + threadIdx.x; e < 3 * Nr; e += gridDim.x * 256) {
    int dir = e / Nr, j = e - dir * Nr;
    int i, stride; float w;
    if (dir == 0) {
      int r = j & 31; int t = j >> 5;
      int g = t % 33; t /= 33;
      i = t * 1089 + g * 33 + r; stride = 1;
      w = (r == 0 || r == 31) ? 2.f : 1.f;
    } else if (dir == 1) {
      int r = j % 33; int t = j / 33; int g = t & 31; t >>= 5;
      i = t * 1089 + g * 33 + r; stride = 33;
      w = (g == 0 || g == 31) ? 2.f : 1.f;
    } else {
      int r = j % 33; int t = j / 33; int g = t % 33; t /= 33;
      int bb = t & 31; t >>= 5;
      i = (t * 33 + bb) * 1089 + g * 33 + r; stride = 1089;
      w = (bb == 0 || bb == 31) ? 2.f : 1.f;
    }
    float d = f[i] - f[i + stride];
    tv = fmaf(d * d, w, tv);
    mn += fmaxf(d, 0.f);
  }
  __shared__ float r1[256], r2[256];
  r1[threadIdx.x] = tv; r2[threadIdx.x] = mn; __syncthreads();
  for (int st = 128; st > 0; st >>= 1) {
    if (threadIdx.x < st) { r1[threadIdx.x] += r1[threadIdx.x + st];
                            r2[threadIdx.x] += r2[threadIdx.x + st]; }
    __syncthreads();
  }
  if (threadIdx.x == 0) {
    atomicAdd(&g_state[GS_ACCS], r1[0]);
    atomicAdd(&g_state[GS_ACCS + 1], r2[0]);
  }
}

// ---------- trilinear apply + blend + clip; finalize tv/mn ----------
__global__ __launch_bounds__(256) void kapply(
    const float* __restrict__ x, const float* __restrict__ F,
    float* __restrict__ out)
{
  int p = blockIdx.x * 256 + threadIdx.x;
  if (p == 0) {
    out[OUT_TV] = g_state[GS_ACCS] * (1.f / 418176.f);
    out[OUT_MN] = g_state[GS_ACCS + 1] * (1.f / 418176.f);
  }
  int b = p >> 20, yx = p & 1048575;
  size_t base = (size_t)b * 3145728u + yx;
  float xr = x[base];
  float xg = x[base + 1048576];
  float xb = x[base + 2097152];
  float a = g_state[GS_BLEND + b];
  float sr = fminf(fmaxf(xr, 0.f), 1.f) * 32.f;
  float sg = fminf(fmaxf(xg, 0.f), 1.f) * 32.f;
  float sb = fminf(fmaxf(xb, 0.f), 1.f) * 32.f;
  int ir = min((int)sr, 31), ig = min((int)sg, 31), ib = min((int)sb, 31);
  float fr = sr - ir, fg = sg - ig, fb = sb - ib;
  const float* Fb = F + (size_t)b * 107811u + ib * 1089 + ig * 33 + ir;
  #pragma unroll
  for (int c = 0; c < 3; c++) {
    const float* Fc = Fb + c * 35937;
    float v000 = Fc[0],    v001 = Fc[1];
    float v010 = Fc[33],   v011 = Fc[34];
    float v100 = Fc[1089], v101 = Fc[1090];
    float v110 = Fc[1122], v111 = Fc[1123];
    float c00 = v000 + fr * (v001 - v000);
    float c01 = v010 + fr * (v011 - v010);
    float c10 = v100 + fr * (v101 - v100);
    float c11 = v110 + fr * (v111 - v110);
    float c0 = c00 + fg * (c01 - c00);
    float c1 = c10 + fg * (c11 - c10);
    float v  = c0 + fb * (c1 - c0);
    float xv = (c == 0) ? xr : (c == 1) ? xg : xb;
    float o = fminf(fmaxf((1.f - a) * xv + a * v, 0.f), 1.f);
    out[(size_t)(b * 3 + c) * 1048576u + yx] = o;
  }
}

extern "C" void kernel_launch(void* const* d_in, const int* in_sizes, int n_in,
                              void* d_out, int out_size, void* d_ws, size_t ws_size,
                              hipStream_t stream)
{
  (void)in_sizes; (void)n_in; (void)out_size;
  const float* x    = (const float*)d_in[0];
  const float* luts = (const float*)d_in[1];
  const float* wn_b1 = (const float*)d_in[3];
  const float* wn_b2 = (const float*)d_in[5];
  const float* wn_b3 = (const float*)d_in[7];
  const float* wn_b4 = (const float*)d_in[9];
  const float* wn_fw1 = (const float*)d_in[10], *wn_fb1 = (const float*)d_in[11];
  const float* wn_fw2 = (const float*)d_in[12], *wn_fb2 = (const float*)d_in[13];
  const float* bl_b1 = (const float*)d_in[15];
  const float* bl_b2 = (const float*)d_in[17];
  const float* bl_b3 = (const float*)d_in[19];
  const float* bl_b4 = (const float*)d_in[21];
  const float* bl_fw1 = (const float*)d_in[22], *bl_fb1 = (const float*)d_in[23];
  const float* bl_fw2 = (const float*)d_in[24], *bl_fb2 = (const float*)d_in[25];
  float* out = (float*)d_out;

  // bf16 scratch for a 2-batch pair: h2 @0 (<=32MB), h3 @32MB (<=16MB);
  // h4 overlays h2 region. Peak 48 MB = d_out chunk 0 (overwritten last).
  u16 *scrA, *scrB;
  if (ws_size >= 50331648u) {
    scrA = (u16*)d_ws;
    scrB = (u16*)d_ws + 16777216;
  } else {
    scrA = (u16*)out;
    scrB = (u16*)out + 16777216;
  }

  PrepArgs pa;
  const float* src[8] = {(const float*)d_in[2], (const float*)d_in[4],
                         (const float*)d_in[6], (const float*)d_in[8],
                         (const float*)d_in[14], (const float*)d_in[16],
                         (const float*)d_in[18], (const float*)d_in[20]};
  const int O[8]   = {32, 32, 64, 64, 16, 16, 32, 32};
  const int IKK[8] = {27, 288, 288, 576, 27, 144, 144, 288};
  const int DST[8] = {WT_WN1, WT_WN2, WT_WN3, WT_WN4,
                      WT_BL1, WT_BL2, WT_BL3, WT_BL4};
  for (int t = 0; t < 8; t++) {
    pa.d[t].src = src[t]; pa.d[t].O = O[t];
    pa.d[t].IKK = IKK[t]; pa.d[t].dst = DST[t];
  }
  kprep<<<dim3(8), 256, 0, stream>>>(pa);

  // ---- weight-net (WN), 2 batches per pass ----
  for (int b0 = 0; b0 < 4; b0 += 2) {
    const float* xb = x + (size_t)b0 * 3145728u;
    k12<32,32><<<dim3(32,32,2), 256, 0, stream>>>(xb, WT_WN1, wn_b1, WT_WN2, wn_b2, scrA);
    k34<32,64,32><<<dim3(16,16,4), 256, 0, stream>>>(scrA, WT_WN3, wn_b3, scrB, 512);
    k34<64,64,16><<<dim3(8,8,8),   256, 0, stream>>>(scrB, WT_WN4, wn_b4, scrA, 256);
    kmean<<<dim3(64,2), 256, 0, stream>>>(scrA, 64, GS_FEATWN + b0 * 64);
  }
  khead<64,8,false><<<1,256,0,stream>>>(wn_fw1, wn_fb1, wn_fw2, wn_fb2,
                                        GS_FEATWN, GS_W3D, out + OUT_W3D);

  // ---- blend-net (BL), 2 batches per pass ----
  for (int b0 = 0; b0 < 4; b0 += 2) {
    const float* xb = x + (size_t)b0 * 3145728u;
    k12<16,16><<<dim3(32,32,2), 256, 0, stream>>>(xb, WT_BL1, bl_b1, WT_BL2, bl_b2, scrA);
    k34<16,32,32><<<dim3(16,16,2), 256, 0, stream>>>(scrA, WT_BL3, bl_b3, scrB, 512);
    k34<32,32,16><<<dim3(8,8,4),   256, 0, stream>>>(scrB, WT_BL4, bl_b4, scrA, 256);
    kmean<<<dim3(32,2), 256, 0, stream>>>(scrA, 32, GS_FEATBL + b0 * 32);
  }
  khead<32,1,true ><<<1,256,0,stream>>>(bl_fw1, bl_fb1, bl_fw2, bl_fb2,
                                        GS_FEATBL, GS_BLEND, (float*)nullptr);

  // ---- LUT fuse, TV, final apply ----
  kfuse<<<1685, 256, 0, stream>>>(luts, out + OUT_FUSED);
  ktv<<<512, 256, 0, stream>>>(out + OUT_FUSED);
  kapply<<<16384, 256, 0, stream>>>(x, out + OUT_FUSED, out);
}